// Round 8
// baseline (776.804 us; speedup 1.0000x reference)
//
#include <hip/hip_runtime.h>
#include <hip/hip_bf16.h>
#include <stdint.h>

typedef __attribute__((ext_vector_type(8))) short bf16x8;
typedef __attribute__((ext_vector_type(4))) float f32x4;
typedef __attribute__((ext_vector_type(16))) float f32x16;

typedef const __attribute__((address_space(1))) void* gas_ptr;
typedef __attribute__((address_space(3))) void* lds_ptr_t;

__device__ __forceinline__ unsigned short f32_to_bf16_rtn(float x) {
    unsigned u = __float_as_uint(x);
    u += 0x7FFFu + ((u >> 16) & 1u);
    return (unsigned short)(u >> 16);
}
__device__ __forceinline__ float bf16_bits_to_f32(unsigned short h) {
    return __uint_as_float(((unsigned)h) << 16);
}

// ---------------------------------------------------------------------------
// Kernel 1: split fp32 inputs into hi/lo bf16 pairs (a = hi + lo, err ~2^-17)
// ---------------------------------------------------------------------------
__global__ __launch_bounds__(256) void split_hi_lo(
    const float* __restrict__ A, const float* __restrict__ B,
    unsigned short* __restrict__ Ahi, unsigned short* __restrict__ Alo,
    unsigned short* __restrict__ Bhi, unsigned short* __restrict__ Blo, int n4)
{
    int i = blockIdx.x * 256 + threadIdx.x;
    if (i >= n4) return;
    float4 a = ((const float4*)A)[i];
    float4 b = ((const float4*)B)[i];
    ushort4 h, l;

    h.x = f32_to_bf16_rtn(a.x); l.x = f32_to_bf16_rtn(a.x - bf16_bits_to_f32(h.x));
    h.y = f32_to_bf16_rtn(a.y); l.y = f32_to_bf16_rtn(a.y - bf16_bits_to_f32(h.y));
    h.z = f32_to_bf16_rtn(a.z); l.z = f32_to_bf16_rtn(a.z - bf16_bits_to_f32(h.z));
    h.w = f32_to_bf16_rtn(a.w); l.w = f32_to_bf16_rtn(a.w - bf16_bits_to_f32(h.w));
    ((ushort4*)Ahi)[i] = h; ((ushort4*)Alo)[i] = l;

    h.x = f32_to_bf16_rtn(b.x); l.x = f32_to_bf16_rtn(b.x - bf16_bits_to_f32(h.x));
    h.y = f32_to_bf16_rtn(b.y); l.y = f32_to_bf16_rtn(b.y - bf16_bits_to_f32(h.y));
    h.z = f32_to_bf16_rtn(b.z); l.z = f32_to_bf16_rtn(b.z - bf16_bits_to_f32(h.z));
    h.w = f32_to_bf16_rtn(b.w); l.w = f32_to_bf16_rtn(b.w - bf16_bits_to_f32(h.w));
    ((ushort4*)Bhi)[i] = h; ((ushort4*)Blo)[i] = l;
}

// ---------------------------------------------------------------------------
// Kernel 2 (presplit, hot path): energies = A @ B^T, split-bf16 3-product GEMM.
// 128x128 block, 4 waves (2x2 of 64x64), dbuf LDS + counted vmcnt(8) (r6).
// r8: 32x32x16 MFMA (r7's refchecked frag/epilogue layouts) with PANELIZED
// staging so LDS reads are byte-identical to r6's measured-0-conflict
// instructions. r7's naive 32x32 read pattern measured 33.5M bank conflicts
// (dur 403); the read map (l&15)*64 + ((l>>4)^((l>>1)&3))*16 + p*1024 is
// proven clean (r4-r6: conflicts == 0). Storage permutation: within each
// 4KB block (64 rows x 32 bf16), panel p = t*2+ks (1KB, 16 rows x 4 slots)
// holds slot (r16,pos) <- data(row = 32t + r16 + 16*(q&1), chunk = 2ks+(q>>1)),
// q = pos ^ ((r16>>1)&3). Then reader lane l (q = l>>4 falls out) receives
// exactly row 32t+(l&31), chunk 2ks+(l>>5) = the 32x32 A/B fragment.
// Half the MFMA instructions (24 vs 48 per K-step) at the faster 32x32 rate
// (2382 vs 2075 TF ubench), same ds_read count, same staging writes.
// ---------------------------------------------------------------------------
__device__ __forceinline__ void wait_vm8_bar()
{
    asm volatile("s_waitcnt vmcnt(8)" ::: "memory");
    __builtin_amdgcn_s_barrier();
    asm volatile("" ::: "memory");
}
__device__ __forceinline__ void wait_vm0_bar()
{
    asm volatile("s_waitcnt vmcnt(0)" ::: "memory");
    __builtin_amdgcn_s_barrier();
    asm volatile("" ::: "memory");
}
__device__ __forceinline__ void bar_only()
{
    asm volatile("" ::: "memory");
    __builtin_amdgcn_s_barrier();
    asm volatile("" ::: "memory");
}

template<int KC, int NC>
__global__ __launch_bounds__(256) void gemm_presplit(
    const __hip_bfloat16* __restrict__ Ahi, const __hip_bfloat16* __restrict__ Alo,
    const __hip_bfloat16* __restrict__ Bhi, const __hip_bfloat16* __restrict__ Blo,
    float* __restrict__ out, int M, int N, int K)
{
    const int Kd = (KC > 0) ? KC : K;   // compile-time when KC>0
    const int Nd = (NC > 0) ? NC : N;

    // Two 32KB buffers: [0,8K)=Ahi [8K,16K)=Alo [16K,24K)=Bhi [24K,32K)=Blo
    __shared__ char sm[65536];
    const int tid  = threadIdx.x;
    const int lane = tid & 63;
    const int w    = tid >> 6;
    const int bm = blockIdx.y, bn = blockIdx.x;
    const int wm = (w >> 1) * 64;
    const int wn = (w & 1) * 64;

    f32x16 acc[2][2] = {};   // 2x2 sub-tiles of 32x32 per wave

    // Panelized staging source mapping (see header comment):
    const int s_t   = (tid >> 7) & 1;
    const int s_ks  = (tid >> 6) & 1;
    const int s_r16 = (tid >> 2) & 15;
    const int s_q   = (tid & 3) ^ ((tid >> 3) & 3);
    const int s_row = s_t * 32 + s_r16 + ((s_q & 1) << 4);
    const int s_ch  = s_ks * 2 + (s_q >> 1);
    const size_t offA = (size_t)(bm * 128 + s_row) * Kd + s_ch * 8;
    const size_t offB = (size_t)(bn * 128 + s_row) * Kd + s_ch * 8;
    const __hip_bfloat16* pAh = Ahi + offA;
    const __hip_bfloat16* pAl = Alo + offA;
    const __hip_bfloat16* pBh = Bhi + offB;
    const __hip_bfloat16* pBl = Blo + offB;
    const size_t half = (size_t)64 * Kd;   // +64 rows (second 4KB block)
    char* dst0 = sm + tid * 16;

    // Read side: EXACT r6 instruction pattern (measured 0 conflicts).
    const int rA  = lane & 15;
    const int ca  = (lane >> 4) ^ ((lane >> 1) & 3);
    const int r31 = lane & 31;
    const char* aP = sm +         (wm >> 6) * 4096 + rA * 64 + ca * 16;  // A-hi
    const char* bP = sm + 16384 + (wn >> 6) * 4096 + rA * 64 + ca * 16;  // B-hi

#define STAGE(BO, kk) do { \
    __builtin_amdgcn_global_load_lds((gas_ptr)(pAh + (kk)),        (lds_ptr_t)(dst0 + (BO)),          16, 0, 0); \
    __builtin_amdgcn_global_load_lds((gas_ptr)(pAh + half + (kk)), (lds_ptr_t)(dst0 + (BO) + 4096),   16, 0, 0); \
    __builtin_amdgcn_global_load_lds((gas_ptr)(pAl + (kk)),        (lds_ptr_t)(dst0 + (BO) + 8192),   16, 0, 0); \
    __builtin_amdgcn_global_load_lds((gas_ptr)(pAl + half + (kk)), (lds_ptr_t)(dst0 + (BO) + 12288),  16, 0, 0); \
    __builtin_amdgcn_global_load_lds((gas_ptr)(pBh + (kk)),        (lds_ptr_t)(dst0 + (BO) + 16384),  16, 0, 0); \
    __builtin_amdgcn_global_load_lds((gas_ptr)(pBh + half + (kk)), (lds_ptr_t)(dst0 + (BO) + 20480),  16, 0, 0); \
    __builtin_amdgcn_global_load_lds((gas_ptr)(pBl + (kk)),        (lds_ptr_t)(dst0 + (BO) + 24576),  16, 0, 0); \
    __builtin_amdgcn_global_load_lds((gas_ptr)(pBl + half + (kk)), (lds_ptr_t)(dst0 + (BO) + 28672),  16, 0, 0); \
} while (0)

#define COMPUTE(BO) do { \
    _Pragma("unroll") \
    for (int ks = 0; ks < 2; ++ks) { \
        bf16x8 ah[2], al[2], bh[2], bl[2]; \
        _Pragma("unroll") \
        for (int t = 0; t < 2; ++t) { \
            const int pnl = (t * 2 + ks) * 1024; \
            ah[t] = *(const bf16x8*)(aP + (BO) + pnl); \
            al[t] = *(const bf16x8*)(aP + (BO) + pnl + 8192); \
            bh[t] = *(const bf16x8*)(bP + (BO) + pnl); \
            bl[t] = *(const bf16x8*)(bP + (BO) + pnl + 8192); \
        } \
        __builtin_amdgcn_s_setprio(1); \
        _Pragma("unroll") \
        for (int im = 0; im < 2; ++im) \
            _Pragma("unroll") \
            for (int jn = 0; jn < 2; ++jn) { \
                acc[im][jn] = __builtin_amdgcn_mfma_f32_32x32x16_bf16(ah[im], bh[jn], acc[im][jn], 0, 0, 0); \
                acc[im][jn] = __builtin_amdgcn_mfma_f32_32x32x16_bf16(al[im], bh[jn], acc[im][jn], 0, 0, 0); \
                acc[im][jn] = __builtin_amdgcn_mfma_f32_32x32x16_bf16(ah[im], bl[jn], acc[im][jn], 0, 0, 0); \
            } \
        __builtin_amdgcn_s_setprio(0); \
    } \
} while (0)

    // Pipeline (r6): stage t+1 into the other buffer, wait own vmcnt to 8,
    // barrier, compute; barrier before overwrite. vmcnt never 0 in the loop.
    STAGE(0, 0);
#pragma unroll 2
    for (int k0 = 0; k0 < Kd - 64; k0 += 64) {
        STAGE(32768, k0 + 32);
        wait_vm8_bar();
        COMPUTE(0);
        bar_only();
        STAGE(0, k0 + 64);
        wait_vm8_bar();
        COMPUTE(32768);
        bar_only();
    }
    // tail: k0 = Kd-64
    STAGE(32768, Kd - 32);
    wait_vm8_bar();
    COMPUTE(0);
    bar_only();
    wait_vm0_bar();
    COMPUTE(32768);

#undef STAGE
#undef COMPUTE

    // Epilogue: 32x32 C/D layout col=lane&31, row=(reg&3)+8*(reg>>2)+4*(lane>>5)
    // (m74/m101; refchecked in r7). NT stores: C is 256 MB (> L3), no reuse.
#pragma unroll
    for (int im = 0; im < 2; ++im)
#pragma unroll
        for (int jn = 0; jn < 2; ++jn) {
            const int rr = bm * 128 + wm + im * 32 + ((lane >> 5) << 2);
            const int cc = bn * 128 + wn + jn * 32 + r31;
#pragma unroll
            for (int g = 0; g < 16; ++g)
                __builtin_nontemporal_store(
                    acc[im][jn][g],
                    &out[(size_t)(rr + (g & 3) + ((g >> 2) << 3)) * Nd + cc]);
        }
}

// ---------------------------------------------------------------------------
// Kernel 2b (fallback, ws too small — not expected to run): inline split,
// 16x16x32 path (kept unchanged from the verified r5 version).
// ---------------------------------------------------------------------------
__global__ __launch_bounds__(256) void gemm_fallback(
    const float* __restrict__ Af, const float* __restrict__ Bf,
    float* __restrict__ out, int M, int N, int K)
{
    __shared__ char sm[32768];
    const int tid  = threadIdx.x;
    const int lane = tid & 63;
    const int w    = tid >> 6;
    const int bm = blockIdx.y, bn = blockIdx.x;
    const int wm = (w >> 1) * 64;
    const int wn = (w & 1) * 64;

    f32x4 acc[4][4] = {};
    const int sfetch = (tid & 3) ^ ((tid >> 3) & 3);
    const int rA = lane & 15;
    const int ca = (lane >> 4) ^ ((lane >> 1) & 3);
    const char* aP = sm +         (wm + rA) * 64 + ca * 16;
    const char* bP = sm + 16384 + (wn + rA) * 64 + ca * 16;

    for (int k0 = 0; k0 < K; k0 += 32) {
        __syncthreads();
#pragma unroll
        for (int c = 0; c < 4; ++c) {
            const bool isA = (c < 2);
            const int row = ((c & 1) << 6) + (tid >> 2);
            const float* src = (isA ? Af + (size_t)(bm * 128 + row) * K
                                    : Bf + (size_t)(bn * 128 + row) * K)
                               + k0 + ((tid & 3) << 3);
            f32x4 v0 = *(const f32x4*)src;
            f32x4 v1 = *(const f32x4*)(src + 4);
            float vv[8] = {v0.x, v0.y, v0.z, v0.w, v1.x, v1.y, v1.z, v1.w};
            bf16x8 h, l;
#pragma unroll
            for (int j = 0; j < 8; ++j) {
                unsigned short hb = f32_to_bf16_rtn(vv[j]);
                unsigned short lb = f32_to_bf16_rtn(vv[j] - bf16_bits_to_f32(hb));
                h[j] = (short)hb; l[j] = (short)lb;
            }
            const int g = row * 64 + sfetch * 16;
            *(bf16x8*)(sm + (isA ? 0 : 16384) + g) = h;
            *(bf16x8*)(sm + (isA ? 8192 : 24576) + g) = l;
        }
        __syncthreads();

        bf16x8 bh[4], bl[4];
#pragma unroll
        for (int j = 0; j < 4; ++j) {
            bh[j] = *(const bf16x8*)(bP + j * 1024);
            bl[j] = *(const bf16x8*)(bP + j * 1024 + 8192);
        }
#pragma unroll
        for (int i = 0; i < 4; ++i) {
            bf16x8 ah = *(const bf16x8*)(aP + i * 1024);
            bf16x8 al = *(const bf16x8*)(aP + i * 1024 + 8192);
#pragma unroll
            for (int j = 0; j < 4; ++j) {
                acc[i][j] = __builtin_amdgcn_mfma_f32_16x16x32_bf16(ah, bh[j], acc[i][j], 0, 0, 0);
                acc[i][j] = __builtin_amdgcn_mfma_f32_16x16x32_bf16(al, bh[j], acc[i][j], 0, 0, 0);
                acc[i][j] = __builtin_amdgcn_mfma_f32_16x16x32_bf16(ah, bl[j], acc[i][j], 0, 0, 0);
            }
        }
    }

    const int r0 = bm * 128 + wm + ((lane >> 4) << 2);
    const int c0 = bn * 128 + wn + rA;
#pragma unroll
    for (int i = 0; i < 4; ++i)
#pragma unroll
        for (int j = 0; j < 4; ++j)
#pragma unroll
            for (int r = 0; r < 4; ++r)
                __builtin_nontemporal_store(
                    acc[i][j][r],
                    &out[(size_t)(r0 + i * 16 + r) * N + (c0 + j * 16)]);
}

// ---------------------------------------------------------------------------
// Kernel 3: in-place row softmax. r0/r1/r3 structural variants all measured
// the same non-gemm remainder (~320-370 us) -> dominated by fixed harness
// overhead (+ ~90us of real BW). Frozen at the r3 version.
// ---------------------------------------------------------------------------
__device__ __forceinline__ void lgkm_barrier()
{
    asm volatile("s_waitcnt lgkmcnt(0)" ::: "memory");
    __builtin_amdgcn_s_barrier();
    asm volatile("" ::: "memory");
}

__device__ __forceinline__ void softmax_row(
    f32x4 (&v)[8], f32x4 (&vn)[8], const f32x4* __restrict__ pn, bool pref,
    f32x4* __restrict__ pout, int tid, int slot,
    float (*smax)[4], float (*ssum)[4])
{
    if (pref) {
#pragma unroll
        for (int i = 0; i < 8; ++i) vn[i] = pn[tid + (i << 8)];
    }
    float m = -3.402823466e+38f;
#pragma unroll
    for (int i = 0; i < 8; ++i)
        m = fmaxf(m, fmaxf(fmaxf(v[i].x, v[i].y), fmaxf(v[i].z, v[i].w)));
#pragma unroll
    for (int o = 32; o >= 1; o >>= 1) m = fmaxf(m, __shfl_xor(m, o));
    if ((tid & 63) == 0) smax[slot][tid >> 6] = m;
    lgkm_barrier();
    m = fmaxf(fmaxf(smax[slot][0], smax[slot][1]), fmaxf(smax[slot][2], smax[slot][3]));

    float s = 0.f;
#pragma unroll
    for (int i = 0; i < 8; ++i) {
        v[i].x = __expf(v[i].x - m);
        v[i].y = __expf(v[i].y - m);
        v[i].z = __expf(v[i].z - m);
        v[i].w = __expf(v[i].w - m);
        s += (v[i].x + v[i].y) + (v[i].z + v[i].w);
    }
#pragma unroll
    for (int o = 32; o >= 1; o >>= 1) s += __shfl_xor(s, o);
    if ((tid & 63) == 0) ssum[slot][tid >> 6] = s;
    lgkm_barrier();
    s = (ssum[slot][0] + ssum[slot][1]) + (ssum[slot][2] + ssum[slot][3]);
    const float r = 1.0f / s;
#pragma unroll
    for (int i = 0; i < 8; ++i) {
        v[i] *= r;
        __builtin_nontemporal_store(v[i], &pout[tid + (i << 8)]);
    }
}

__global__ __launch_bounds__(256) void softmax_rows_8192(float* __restrict__ d)
{
    const int tid = threadIdx.x;
    __shared__ float smax[2][4], ssum[2][4];

    f32x4* p0 = (f32x4*)(d + (size_t)blockIdx.x * 4 * 8192);
    f32x4 va[8], vb[8];
#pragma unroll
    for (int i = 0; i < 8; ++i) va[i] = p0[tid + (i << 8)];

    softmax_row(va, vb, p0 + 2048, true,  p0,        tid, 0, smax, ssum);
    softmax_row(vb, va, p0 + 4096, true,  p0 + 2048, tid, 1, smax, ssum);
    softmax_row(va, vb, p0 + 6144, true,  p0 + 4096, tid, 0, smax, ssum);
    softmax_row(vb, va, p0,        false, p0 + 6144, tid, 1, smax, ssum);
}

// ---------------------------------------------------------------------------
extern "C" void kernel_launch(void* const* d_in, const int* in_sizes, int n_in,
                              void* d_out, int out_size, void* d_ws, size_t ws_size,
                              hipStream_t stream)
{
    const float* A = (const float*)d_in[0];   // user_emb [M, K] fp32
    const float* B = (const float*)d_in[1];   // id_emb   [N, K] fp32
    float* out = (float*)d_out;               // [M, N] fp32
    const int K = 1024;
    const int M = in_sizes[0] / K;
    const int N = in_sizes[1] / K;
    const size_t elemsA = (size_t)M * K;
    const size_t elemsB = (size_t)N * K;
    const size_t need = 2 * (elemsA + elemsB) * sizeof(unsigned short);

    dim3 grid(N / 128, M / 128);
    const bool presplit = (ws_size >= need) && (M == N) && (K % 64 == 0) && (K >= 128);

    if (presplit) {
        unsigned short* Ahi = (unsigned short*)d_ws;
        unsigned short* Alo = Ahi + elemsA;
        unsigned short* Bhi = Alo + elemsA;
        unsigned short* Blo = Bhi + elemsB;
        const int n4 = (int)(elemsA / 4);
        split_hi_lo<<<(n4 + 255) / 256, 256, 0, stream>>>(A, B, Ahi, Alo, Bhi, Blo, n4);
        if (K == 1024 && N == 8192) {
            gemm_presplit<1024, 8192><<<grid, 256, 0, stream>>>(
                (const __hip_bfloat16*)Ahi, (const __hip_bfloat16*)Alo,
                (const __hip_bfloat16*)Bhi, (const __hip_bfloat16*)Blo,
                out, M, N, K);
        } else {
            gemm_presplit<0, 0><<<grid, 256, 0, stream>>>(
                (const __hip_bfloat16*)Ahi, (const __hip_bfloat16*)Alo,
                (const __hip_bfloat16*)Bhi, (const __hip_bfloat16*)Blo,
                out, M, N, K);
        }
    } else {
        gemm_fallback<<<grid, 256, 0, stream>>>(A, B, out, M, N, K);
    }
    softmax_rows_8192<<<M / 4, 256, 0, stream>>>(out);
}

// Round 9
// 752.343 us; speedup vs baseline: 1.0325x; 1.0325x over previous
//
#include <hip/hip_runtime.h>
#include <hip/hip_bf16.h>
#include <stdint.h>

typedef __attribute__((ext_vector_type(8))) short bf16x8;
typedef __attribute__((ext_vector_type(4))) float f32x4;

typedef const __attribute__((address_space(1))) void* gas_ptr;
typedef __attribute__((address_space(3))) void* lds_ptr_t;

__device__ __forceinline__ unsigned short f32_to_bf16_rtn(float x) {
    unsigned u = __float_as_uint(x);
    u += 0x7FFFu + ((u >> 16) & 1u);
    return (unsigned short)(u >> 16);
}
__device__ __forceinline__ float bf16_bits_to_f32(unsigned short h) {
    return __uint_as_float(((unsigned)h) << 16);
}

__device__ __forceinline__ void wait_vm8_bar()
{
    asm volatile("s_waitcnt vmcnt(8)" ::: "memory");
    __builtin_amdgcn_s_barrier();
    asm volatile("" ::: "memory");
}
__device__ __forceinline__ void wait_vm0_bar()
{
    asm volatile("s_waitcnt vmcnt(0)" ::: "memory");
    __builtin_amdgcn_s_barrier();
    asm volatile("" ::: "memory");
}
__device__ __forceinline__ void bar_only()
{
    asm volatile("" ::: "memory");
    __builtin_amdgcn_s_barrier();
    asm volatile("" ::: "memory");
}

// ---------------------------------------------------------------------------
// Kernel 1: split fp32 inputs into hi/lo bf16 pairs (a = hi + lo, err ~2^-17)
// ---------------------------------------------------------------------------
__global__ __launch_bounds__(256) void split_hi_lo(
    const float* __restrict__ A, const float* __restrict__ B,
    unsigned short* __restrict__ Ahi, unsigned short* __restrict__ Alo,
    unsigned short* __restrict__ Bhi, unsigned short* __restrict__ Blo, int n4)
{
    int i = blockIdx.x * 256 + threadIdx.x;
    if (i >= n4) return;
    float4 a = ((const float4*)A)[i];
    float4 b = ((const float4*)B)[i];
    ushort4 h, l;

    h.x = f32_to_bf16_rtn(a.x); l.x = f32_to_bf16_rtn(a.x - bf16_bits_to_f32(h.x));
    h.y = f32_to_bf16_rtn(a.y); l.y = f32_to_bf16_rtn(a.y - bf16_bits_to_f32(h.y));
    h.z = f32_to_bf16_rtn(a.z); l.z = f32_to_bf16_rtn(a.z - bf16_bits_to_f32(h.z));
    h.w = f32_to_bf16_rtn(a.w); l.w = f32_to_bf16_rtn(a.w - bf16_bits_to_f32(h.w));
    ((ushort4*)Ahi)[i] = h; ((ushort4*)Alo)[i] = l;

    h.x = f32_to_bf16_rtn(b.x); l.x = f32_to_bf16_rtn(b.x - bf16_bits_to_f32(h.x));
    h.y = f32_to_bf16_rtn(b.y); l.y = f32_to_bf16_rtn(b.y - bf16_bits_to_f32(h.y));
    h.z = f32_to_bf16_rtn(b.z); l.z = f32_to_bf16_rtn(b.z - bf16_bits_to_f32(h.z));
    h.w = f32_to_bf16_rtn(b.w); l.w = f32_to_bf16_rtn(b.w - bf16_bits_to_f32(h.w));
    ((ushort4*)Bhi)[i] = h; ((ushort4*)Blo)[i] = l;
}

// ---------------------------------------------------------------------------
// Kernel 2 (hot path, M=N=8192 K=1024): 256x256 tile, split-bf16 3-product.
// r9: SAME sync skeleton as r6 (best measured GEMM: 352us, conflicts 0,
// MfmaUtil 55) — dbuf LDS + counted vmcnt(8) + raw barriers + setprio —
// but BM=BN=256, 8 waves (2x4), 512 threads. Mechanism: compute density.
// r6 ran 48 MFMA/wave per 8 staged loads (6 MFMA/KB); this runs 96 MFMA/wave
// per 8 loads (12 MFMA/KB) -> staging latency and barrier cost amortized 2x.
// r7/r8 lesson: 32x32 shape loses on ILP even at 0 conflicts (400us, util
// 48.6) -> 16x16x32 kept. LDS 2x64KB dynamic (m201 precedent at 128KB).
// Per-K-step: 8 gload_lds/thread, 24 ds_read_b128/wave, 96 MFMA/wave.
// LDS image per buffer: [0,16K)=Ahi [16K,32K)=Alo [32K,48K)=Bhi [48K,64K)=Blo;
// each 16KB = 4x 4KB blocks (64 rows x 32 bf16, XOR-swizzled 16B chunks,
// proven-0-conflict read map rA*64 + ((l>>4)^((l>>1)&3))*16 + blockoffs).
// FP chain per output element identical to r6 -> absmax must stay 0.00390625.
// ---------------------------------------------------------------------------
template<int KC, int NC>
__global__ __launch_bounds__(512) void gemm_presplit256(
    const __hip_bfloat16* __restrict__ Ahi, const __hip_bfloat16* __restrict__ Alo,
    const __hip_bfloat16* __restrict__ Bhi, const __hip_bfloat16* __restrict__ Blo,
    float* __restrict__ out)
{
    const int Kd = KC;
    const int Nd = NC;
    extern __shared__ char sm[];   // 131072 B: two 64KB buffers

    const int tid  = threadIdx.x;
    const int lane = tid & 63;
    const int w    = tid >> 6;          // 0..7
    const int bm = blockIdx.y, bn = blockIdx.x;
    const int wm = (w >> 2) * 128;      // 0 or 128
    const int wn = (w & 3) * 64;        // 0,64,128,192

    f32x4 acc[8][4] = {};               // 128 VGPR-equivalents

    // Staging (identical formula family to r6): thread owns LDS chunk
    // (row128 = tid>>2, pos = tid&3) within each 8KB half; fetches source
    // chunk sfetch = (tid&3) ^ ((tid>>3)&3)  [= pos ^ ((row>>1)&3)].
    const int sfetch = (tid & 3) ^ ((tid >> 3) & 3);
    const size_t offA = (size_t)(bm * 256 + (tid >> 2)) * Kd + sfetch * 8;
    const size_t offB = (size_t)(bn * 256 + (tid >> 2)) * Kd + sfetch * 8;
    const __hip_bfloat16* pAh = Ahi + offA;
    const __hip_bfloat16* pAl = Alo + offA;
    const __hip_bfloat16* pBh = Bhi + offB;
    const __hip_bfloat16* pBl = Blo + offB;
    const size_t half = (size_t)128 * Kd;   // +128 rows (second 8KB half)
    char* dst0 = sm + tid * 16;

    // Read side: r6's proven-0-conflict per-lane pattern.
    const int rA = lane & 15;
    const int ca = (lane >> 4) ^ ((lane >> 1) & 3);
    const char* aP = sm +         (wm >> 6) * 4096 + rA * 64 + ca * 16;  // A-hi
    const char* bP = sm + 32768 + (wn >> 6) * 4096 + rA * 64 + ca * 16;  // B-hi

#define STAGE(BO, kk) do { \
    __builtin_amdgcn_global_load_lds((gas_ptr)(pAh + (kk)),        (lds_ptr_t)(dst0 + (BO)),          16, 0, 0); \
    __builtin_amdgcn_global_load_lds((gas_ptr)(pAh + half + (kk)), (lds_ptr_t)(dst0 + (BO) + 8192),   16, 0, 0); \
    __builtin_amdgcn_global_load_lds((gas_ptr)(pAl + (kk)),        (lds_ptr_t)(dst0 + (BO) + 16384),  16, 0, 0); \
    __builtin_amdgcn_global_load_lds((gas_ptr)(pAl + half + (kk)), (lds_ptr_t)(dst0 + (BO) + 24576),  16, 0, 0); \
    __builtin_amdgcn_global_load_lds((gas_ptr)(pBh + (kk)),        (lds_ptr_t)(dst0 + (BO) + 32768),  16, 0, 0); \
    __builtin_amdgcn_global_load_lds((gas_ptr)(pBh + half + (kk)), (lds_ptr_t)(dst0 + (BO) + 40960),  16, 0, 0); \
    __builtin_amdgcn_global_load_lds((gas_ptr)(pBl + (kk)),        (lds_ptr_t)(dst0 + (BO) + 49152),  16, 0, 0); \
    __builtin_amdgcn_global_load_lds((gas_ptr)(pBl + half + (kk)), (lds_ptr_t)(dst0 + (BO) + 57344),  16, 0, 0); \
} while (0)

#define COMPUTE(BO) do { \
    bf16x8 bh[4], bl[4]; \
    _Pragma("unroll") \
    for (int j = 0; j < 4; ++j) { \
        bh[j] = *(const bf16x8*)(bP + (BO) + j * 1024); \
        bl[j] = *(const bf16x8*)(bP + (BO) + j * 1024 + 16384); \
    } \
    __builtin_amdgcn_s_setprio(1); \
    _Pragma("unroll") \
    for (int i = 0; i < 8; ++i) { \
        const int ao = ((i >> 2) << 12) + ((i & 3) << 10); \
        bf16x8 ah = *(const bf16x8*)(aP + (BO) + ao); \
        bf16x8 al = *(const bf16x8*)(aP + (BO) + ao + 16384); \
        _Pragma("unroll") \
        for (int j = 0; j < 4; ++j) { \
            acc[i][j] = __builtin_amdgcn_mfma_f32_16x16x32_bf16(ah, bh[j], acc[i][j], 0, 0, 0); \
            acc[i][j] = __builtin_amdgcn_mfma_f32_16x16x32_bf16(al, bh[j], acc[i][j], 0, 0, 0); \
            acc[i][j] = __builtin_amdgcn_mfma_f32_16x16x32_bf16(ah, bl[j], acc[i][j], 0, 0, 0); \
        } \
    } \
    __builtin_amdgcn_s_setprio(0); \
} while (0)

    // r6 pipeline: stage next tile into the other buffer; own vmcnt to 8
    // (current buffer's 8 loads landed) + barrier; compute; barrier before
    // the buffer is overwritten. vmcnt never drains to 0 inside the loop.
    STAGE(0, 0);
#pragma unroll 2
    for (int k0 = 0; k0 < Kd - 64; k0 += 64) {
        STAGE(65536, k0 + 32);
        wait_vm8_bar();
        COMPUTE(0);
        bar_only();
        STAGE(0, k0 + 64);
        wait_vm8_bar();
        COMPUTE(65536);
        bar_only();
    }
    // tail: last two tiles
    STAGE(65536, Kd - 32);
    wait_vm8_bar();
    COMPUTE(0);
    bar_only();
    wait_vm0_bar();
    COMPUTE(65536);

#undef STAGE
#undef COMPUTE

    // Epilogue: 16x16 C/D layout col=lane&15, row=(lane>>4)*4+reg (m89/m91).
    // NT stores: C is 256 MB (> L3), zero reuse before softmax streams it.
    const int r0 = bm * 256 + wm + ((lane >> 4) << 2);
    const int c0 = bn * 256 + wn + rA;
#pragma unroll
    for (int i = 0; i < 8; ++i)
#pragma unroll
        for (int j = 0; j < 4; ++j)
#pragma unroll
            for (int r = 0; r < 4; ++r)
                __builtin_nontemporal_store(
                    acc[i][j][r],
                    &out[(size_t)(r0 + i * 16 + r) * Nd + (c0 + j * 16)]);
}

// ---------------------------------------------------------------------------
// Kernel 2b (generic presplit path, off-shape only): r6's verified 128x128
// 16x16x32 kernel with runtime dims.
// ---------------------------------------------------------------------------
__global__ __launch_bounds__(256) void gemm_presplit128(
    const __hip_bfloat16* __restrict__ Ahi, const __hip_bfloat16* __restrict__ Alo,
    const __hip_bfloat16* __restrict__ Bhi, const __hip_bfloat16* __restrict__ Blo,
    float* __restrict__ out, int M, int N, int K)
{
    __shared__ char sm[65536];
    const int tid  = threadIdx.x;
    const int lane = tid & 63;
    const int w    = tid >> 6;
    const int bm = blockIdx.y, bn = blockIdx.x;
    const int wm = (w >> 1) * 64;
    const int wn = (w & 1) * 64;

    f32x4 acc[4][4] = {};

    const int sfetch = (tid & 3) ^ ((tid >> 3) & 3);
    const size_t offA = (size_t)(bm * 128 + (tid >> 2)) * K + sfetch * 8;
    const size_t offB = (size_t)(bn * 128 + (tid >> 2)) * K + sfetch * 8;
    const __hip_bfloat16* pAh = Ahi + offA;
    const __hip_bfloat16* pAl = Alo + offA;
    const __hip_bfloat16* pBh = Bhi + offB;
    const __hip_bfloat16* pBl = Blo + offB;
    const size_t half = (size_t)64 * K;
    char* dst0 = sm + tid * 16;

    const int rA = lane & 15;
    const int ca = (lane >> 4) ^ ((lane >> 1) & 3);
    const char* aP = sm +         (wm + rA) * 64 + ca * 16;
    const char* bP = sm + 16384 + (wn + rA) * 64 + ca * 16;

#define STAGE(BO, kk) do { \
    __builtin_amdgcn_global_load_lds((gas_ptr)(pAh + (kk)),        (lds_ptr_t)(dst0 + (BO)),          16, 0, 0); \
    __builtin_amdgcn_global_load_lds((gas_ptr)(pAh + half + (kk)), (lds_ptr_t)(dst0 + (BO) + 4096),   16, 0, 0); \
    __builtin_amdgcn_global_load_lds((gas_ptr)(pAl + (kk)),        (lds_ptr_t)(dst0 + (BO) + 8192),   16, 0, 0); \
    __builtin_amdgcn_global_load_lds((gas_ptr)(pAl + half + (kk)), (lds_ptr_t)(dst0 + (BO) + 12288),  16, 0, 0); \
    __builtin_amdgcn_global_load_lds((gas_ptr)(pBh + (kk)),        (lds_ptr_t)(dst0 + (BO) + 16384),  16, 0, 0); \
    __builtin_amdgcn_global_load_lds((gas_ptr)(pBh + half + (kk)), (lds_ptr_t)(dst0 + (BO) + 20480),  16, 0, 0); \
    __builtin_amdgcn_global_load_lds((gas_ptr)(pBl + (kk)),        (lds_ptr_t)(dst0 + (BO) + 24576),  16, 0, 0); \
    __builtin_amdgcn_global_load_lds((gas_ptr)(pBl + half + (kk)), (lds_ptr_t)(dst0 + (BO) + 28672),  16, 0, 0); \
} while (0)

#define COMPUTE(BO) do { \
    bf16x8 bh[4], bl[4]; \
    _Pragma("unroll") \
    for (int j = 0; j < 4; ++j) { \
        bh[j] = *(const bf16x8*)(bP + (BO) + j * 1024); \
        bl[j] = *(const bf16x8*)(bP + (BO) + j * 1024 + 8192); \
    } \
    __builtin_amdgcn_s_setprio(1); \
    _Pragma("unroll") \
    for (int i = 0; i < 4; ++i) { \
        bf16x8 ah = *(const bf16x8*)(aP + (BO) + i * 1024); \
        bf16x8 al = *(const bf16x8*)(aP + (BO) + i * 1024 + 8192); \
        _Pragma("unroll") \
        for (int j = 0; j < 4; ++j) { \
            acc[i][j] = __builtin_amdgcn_mfma_f32_16x16x32_bf16(ah, bh[j], acc[i][j], 0, 0, 0); \
            acc[i][j] = __builtin_amdgcn_mfma_f32_16x16x32_bf16(al, bh[j], acc[i][j], 0, 0, 0); \
            acc[i][j] = __builtin_amdgcn_mfma_f32_16x16x32_bf16(ah, bl[j], acc[i][j], 0, 0, 0); \
        } \
    } \
    __builtin_amdgcn_s_setprio(0); \
} while (0)

    STAGE(0, 0);
    for (int k0 = 0; k0 < K - 64; k0 += 64) {
        STAGE(32768, k0 + 32);
        wait_vm8_bar();
        COMPUTE(0);
        bar_only();
        STAGE(0, k0 + 64);
        wait_vm8_bar();
        COMPUTE(32768);
        bar_only();
    }
    STAGE(32768, K - 32);
    wait_vm8_bar();
    COMPUTE(0);
    bar_only();
    wait_vm0_bar();
    COMPUTE(32768);

#undef STAGE
#undef COMPUTE

    const int r0 = bm * 128 + wm + ((lane >> 4) << 2);
    const int c0 = bn * 128 + wn + rA;
#pragma unroll
    for (int i = 0; i < 4; ++i)
#pragma unroll
        for (int j = 0; j < 4; ++j)
#pragma unroll
            for (int r = 0; r < 4; ++r)
                __builtin_nontemporal_store(
                    acc[i][j][r],
                    &out[(size_t)(r0 + i * 16 + r) * N + (c0 + j * 16)]);
}

// ---------------------------------------------------------------------------
// Kernel 2c (fallback, ws too small — not expected to run): inline split.
// ---------------------------------------------------------------------------
__global__ __launch_bounds__(256) void gemm_fallback(
    const float* __restrict__ Af, const float* __restrict__ Bf,
    float* __restrict__ out, int M, int N, int K)
{
    __shared__ char sm[32768];
    const int tid  = threadIdx.x;
    const int lane = tid & 63;
    const int w    = tid >> 6;
    const int bm = blockIdx.y, bn = blockIdx.x;
    const int wm = (w >> 1) * 64;
    const int wn = (w & 1) * 64;

    f32x4 acc[4][4] = {};
    const int sfetch = (tid & 3) ^ ((tid >> 3) & 3);
    const int rA = lane & 15;
    const int ca = (lane >> 4) ^ ((lane >> 1) & 3);
    const char* aP = sm +         (wm + rA) * 64 + ca * 16;
    const char* bP = sm + 16384 + (wn + rA) * 64 + ca * 16;

    for (int k0 = 0; k0 < K; k0 += 32) {
        __syncthreads();
#pragma unroll
        for (int c = 0; c < 4; ++c) {
            const bool isA = (c < 2);
            const int row = ((c & 1) << 6) + (tid >> 2);
            const float* src = (isA ? Af + (size_t)(bm * 128 + row) * K
                                    : Bf + (size_t)(bn * 128 + row) * K)
                               + k0 + ((tid & 3) << 3);
            f32x4 v0 = *(const f32x4*)src;
            f32x4 v1 = *(const f32x4*)(src + 4);
            float vv[8] = {v0.x, v0.y, v0.z, v0.w, v1.x, v1.y, v1.z, v1.w};
            bf16x8 h, l;
#pragma unroll
            for (int j = 0; j < 8; ++j) {
                unsigned short hb = f32_to_bf16_rtn(vv[j]);
                unsigned short lb = f32_to_bf16_rtn(vv[j] - bf16_bits_to_f32(hb));
                h[j] = (short)hb; l[j] = (short)lb;
            }
            const int g = row * 64 + sfetch * 16;
            *(bf16x8*)(sm + (isA ? 0 : 16384) + g) = h;
            *(bf16x8*)(sm + (isA ? 8192 : 24576) + g) = l;
        }
        __syncthreads();

        bf16x8 bh[4], bl[4];
#pragma unroll
        for (int j = 0; j < 4; ++j) {
            bh[j] = *(const bf16x8*)(bP + j * 1024);
            bl[j] = *(const bf16x8*)(bP + j * 1024 + 8192);
        }
#pragma unroll
        for (int i = 0; i < 4; ++i) {
            bf16x8 ah = *(const bf16x8*)(aP + i * 1024);
            bf16x8 al = *(const bf16x8*)(aP + i * 1024 + 8192);
#pragma unroll
            for (int j = 0; j < 4; ++j) {
                acc[i][j] = __builtin_amdgcn_mfma_f32_16x16x32_bf16(ah, bh[j], acc[i][j], 0, 0, 0);
                acc[i][j] = __builtin_amdgcn_mfma_f32_16x16x32_bf16(al, bh[j], acc[i][j], 0, 0, 0);
                acc[i][j] = __builtin_amdgcn_mfma_f32_16x16x32_bf16(ah, bl[j], acc[i][j], 0, 0, 0);
            }
        }
    }

    const int r0 = bm * 128 + wm + ((lane >> 4) << 2);
    const int c0 = bn * 128 + wn + rA;
#pragma unroll
    for (int i = 0; i < 4; ++i)
#pragma unroll
        for (int j = 0; j < 4; ++j)
#pragma unroll
            for (int r = 0; r < 4; ++r)
                __builtin_nontemporal_store(
                    acc[i][j][r],
                    &out[(size_t)(r0 + i * 16 + r) * N + (c0 + j * 16)]);
}

// ---------------------------------------------------------------------------
// Kernel 3: in-place row softmax. r0/r1/r3 structural variants all measured
// the same non-gemm remainder (~320-370 us) -> dominated by fixed harness
// overhead (+ ~90us of real BW). Frozen at the r3 version.
// ---------------------------------------------------------------------------
__device__ __forceinline__ void lgkm_barrier()
{
    asm volatile("s_waitcnt lgkmcnt(0)" ::: "memory");
    __builtin_amdgcn_s_barrier();
    asm volatile("" ::: "memory");
}

__device__ __forceinline__ void softmax_row(
    f32x4 (&v)[8], f32x4 (&vn)[8], const f32x4* __restrict__ pn, bool pref,
    f32x4* __restrict__ pout, int tid, int slot,
    float (*smax)[4], float (*ssum)[4])
{
    if (pref) {
#pragma unroll
        for (int i = 0; i < 8; ++i) vn[i] = pn[tid + (i << 8)];
    }
    float m = -3.402823466e+38f;
#pragma unroll
    for (int i = 0; i < 8; ++i)
        m = fmaxf(m, fmaxf(fmaxf(v[i].x, v[i].y), fmaxf(v[i].z, v[i].w)));
#pragma unroll
    for (int o = 32; o >= 1; o >>= 1) m = fmaxf(m, __shfl_xor(m, o));
    if ((tid & 63) == 0) smax[slot][tid >> 6] = m;
    lgkm_barrier();
    m = fmaxf(fmaxf(smax[slot][0], smax[slot][1]), fmaxf(smax[slot][2], smax[slot][3]));

    float s = 0.f;
#pragma unroll
    for (int i = 0; i < 8; ++i) {
        v[i].x = __expf(v[i].x - m);
        v[i].y = __expf(v[i].y - m);
        v[i].z = __expf(v[i].z - m);
        v[i].w = __expf(v[i].w - m);
        s += (v[i].x + v[i].y) + (v[i].z + v[i].w);
    }
#pragma unroll
    for (int o = 32; o >= 1; o >>= 1) s += __shfl_xor(s, o);
    if ((tid & 63) == 0) ssum[slot][tid >> 6] = s;
    lgkm_barrier();
    s = (ssum[slot][0] + ssum[slot][1]) + (ssum[slot][2] + ssum[slot][3]);
    const float r = 1.0f / s;
#pragma unroll
    for (int i = 0; i < 8; ++i) {
        v[i] *= r;
        __builtin_nontemporal_store(v[i], &pout[tid + (i << 8)]);
    }
}

__global__ __launch_bounds__(256) void softmax_rows_8192(float* __restrict__ d)
{
    const int tid = threadIdx.x;
    __shared__ float smax[2][4], ssum[2][4];

    f32x4* p0 = (f32x4*)(d + (size_t)blockIdx.x * 4 * 8192);
    f32x4 va[8], vb[8];
#pragma unroll
    for (int i = 0; i < 8; ++i) va[i] = p0[tid + (i << 8)];

    softmax_row(va, vb, p0 + 2048, true,  p0,        tid, 0, smax, ssum);
    softmax_row(vb, va, p0 + 4096, true,  p0 + 2048, tid, 1, smax, ssum);
    softmax_row(va, vb, p0 + 6144, true,  p0 + 4096, tid, 0, smax, ssum);
    softmax_row(vb, va, p0,        false, p0 + 6144, tid, 1, smax, ssum);
}

// ---------------------------------------------------------------------------
extern "C" void kernel_launch(void* const* d_in, const int* in_sizes, int n_in,
                              void* d_out, int out_size, void* d_ws, size_t ws_size,
                              hipStream_t stream)
{
    const float* A = (const float*)d_in[0];   // user_emb [M, K] fp32
    const float* B = (const float*)d_in[1];   // id_emb   [N, K] fp32
    float* out = (float*)d_out;               // [M, N] fp32
    const int K = 1024;
    const int M = in_sizes[0] / K;
    const int N = in_sizes[1] / K;
    const size_t elemsA = (size_t)M * K;
    const size_t elemsB = (size_t)N * K;
    const size_t need = 2 * (elemsA + elemsB) * sizeof(unsigned short);

    const bool presplit = (ws_size >= need) && (M == N) && (K % 64 == 0) && (K >= 128);

    if (presplit) {
        unsigned short* Ahi = (unsigned short*)d_ws;
        unsigned short* Alo = Ahi + elemsA;
        unsigned short* Bhi = Alo + elemsA;
        unsigned short* Blo = Bhi + elemsB;
        const int n4 = (int)(elemsA / 4);
        split_hi_lo<<<(n4 + 255) / 256, 256, 0, stream>>>(A, B, Ahi, Alo, Bhi, Blo, n4);
        if (M == 8192 && N == 8192 && K == 1024) {
            dim3 grid(N / 256, M / 256);
            gemm_presplit256<1024, 8192><<<grid, 512, 131072, stream>>>(
                (const __hip_bfloat16*)Ahi, (const __hip_bfloat16*)Alo,
                (const __hip_bfloat16*)Bhi, (const __hip_bfloat16*)Blo, out);
        } else {
            dim3 grid(N / 128, M / 128);
            gemm_presplit128<<<grid, 256, 0, stream>>>(
                (const __hip_bfloat16*)Ahi, (const __hip_bfloat16*)Alo,
                (const __hip_bfloat16*)Bhi, (const __hip_bfloat16*)Blo,
                out, M, N, K);
        }
    } else {
        dim3 grid(N / 128, M / 128);
        gemm_fallback<<<grid, 256, 0, stream>>>(A, B, out, M, N, K);
    }
    softmax_rows_8192<<<M / 4, 256, 0, stream>>>(out);
}

// Round 10
// 727.194 us; speedup vs baseline: 1.0682x; 1.0346x over previous
//
#include <hip/hip_runtime.h>
#include <hip/hip_bf16.h>
#include <stdint.h>

typedef __attribute__((ext_vector_type(8))) short bf16x8;
typedef __attribute__((ext_vector_type(4))) float f32x4;

typedef const __attribute__((address_space(1))) void* gas_ptr;
typedef __attribute__((address_space(3))) void* lds_ptr_t;

__device__ __forceinline__ unsigned short f32_to_bf16_rtn(float x) {
    unsigned u = __float_as_uint(x);
    u += 0x7FFFu + ((u >> 16) & 1u);
    return (unsigned short)(u >> 16);
}
__device__ __forceinline__ float bf16_bits_to_f32(unsigned short h) {
    return __uint_as_float(((unsigned)h) << 16);
}

// ---------------------------------------------------------------------------
// Kernel 1: split fp32 inputs into hi/lo bf16 pairs (a = hi + lo, err ~2^-17)
// ---------------------------------------------------------------------------
__global__ __launch_bounds__(256) void split_hi_lo(
    const float* __restrict__ A, const float* __restrict__ B,
    unsigned short* __restrict__ Ahi, unsigned short* __restrict__ Alo,
    unsigned short* __restrict__ Bhi, unsigned short* __restrict__ Blo, int n4)
{
    int i = blockIdx.x * 256 + threadIdx.x;
    if (i >= n4) return;
    float4 a = ((const float4*)A)[i];
    float4 b = ((const float4*)B)[i];
    ushort4 h, l;

    h.x = f32_to_bf16_rtn(a.x); l.x = f32_to_bf16_rtn(a.x - bf16_bits_to_f32(h.x));
    h.y = f32_to_bf16_rtn(a.y); l.y = f32_to_bf16_rtn(a.y - bf16_bits_to_f32(h.y));
    h.z = f32_to_bf16_rtn(a.z); l.z = f32_to_bf16_rtn(a.z - bf16_bits_to_f32(h.z));
    h.w = f32_to_bf16_rtn(a.w); l.w = f32_to_bf16_rtn(a.w - bf16_bits_to_f32(h.w));
    ((ushort4*)Ahi)[i] = h; ((ushort4*)Alo)[i] = l;

    h.x = f32_to_bf16_rtn(b.x); l.x = f32_to_bf16_rtn(b.x - bf16_bits_to_f32(h.x));
    h.y = f32_to_bf16_rtn(b.y); l.y = f32_to_bf16_rtn(b.y - bf16_bits_to_f32(h.y));
    h.z = f32_to_bf16_rtn(b.z); l.z = f32_to_bf16_rtn(b.z - bf16_bits_to_f32(h.z));
    h.w = f32_to_bf16_rtn(b.w); l.w = f32_to_bf16_rtn(b.w - bf16_bits_to_f32(h.w));
    ((ushort4*)Bhi)[i] = h; ((ushort4*)Blo)[i] = l;
}

// ---------------------------------------------------------------------------
// Kernel 2 (presplit, hot path): energies = A @ B^T, split-bf16 3-product GEMM.
// FINAL (r10 = r6 revert): best-measured GEMM of the session — 352 us,
// SQ_LDS_BANK_CONFLICT 0, MfmaUtil 55, VALUBusy 17.
// Structure: 128x128 block, 4 waves (2x2 of 64x64), 16x16x32 mfma,
// constexpr dims + unroll x4 (r4: VALU 43->23.6), NT C-stores (r5),
// dbuf LDS 2x32KB + counted vmcnt(8) + raw barriers + setprio (r6),
// XOR-swizzled 16B chunks (measured 0 conflicts).
// Session ledger (each single-variable change measured):
//   r1 XCD swizzle: FETCH 323->1400 MB, util 52->37  -> REVERTED
//   r4 constexpr+unroll: VALU 43->23.6, dur -2%      -> KEPT
//   r5 NT C-stores: FETCH -10%, dur -3%              -> KEPT
//   r6 dbuf+vm8+setprio: dur -3%                     -> KEPT (this kernel)
//   r7 32x32x16 naive: 33.5M conflicts, 403 us       -> REVERTED
//   r8 32x32x16 panelized: conflicts 0 BUT 400 us    -> REVERTED (ILP loss)
//   r9 256x256 tile: FETCH 197 MB but 399 us, util 45-> REVERTED
// Conclusion: 2-phase structural plateau at ~55% MfmaUtil; the measured
// path beyond is the full co-designed 8-phase 256^2 schedule (learn_hip
// m194-m201), whose components are null/negative as grafts (m196/m232, r9).
// ---------------------------------------------------------------------------
__device__ __forceinline__ void wait_vm8_bar()
{
    asm volatile("s_waitcnt vmcnt(8)" ::: "memory");
    __builtin_amdgcn_s_barrier();
    asm volatile("" ::: "memory");
}
__device__ __forceinline__ void wait_vm0_bar()
{
    asm volatile("s_waitcnt vmcnt(0)" ::: "memory");
    __builtin_amdgcn_s_barrier();
    asm volatile("" ::: "memory");
}
__device__ __forceinline__ void bar_only()
{
    asm volatile("" ::: "memory");
    __builtin_amdgcn_s_barrier();
    asm volatile("" ::: "memory");
}

template<int KC, int NC>
__global__ __launch_bounds__(256) void gemm_presplit(
    const __hip_bfloat16* __restrict__ Ahi, const __hip_bfloat16* __restrict__ Alo,
    const __hip_bfloat16* __restrict__ Bhi, const __hip_bfloat16* __restrict__ Blo,
    float* __restrict__ out, int M, int N, int K)
{
    const int Kd = (KC > 0) ? KC : K;   // compile-time when KC>0
    const int Nd = (NC > 0) ? NC : N;

    // Two 32KB buffers: [0,8K)=Ahi [8K,16K)=Alo [16K,24K)=Bhi [24K,32K)=Blo
    __shared__ char sm[65536];
    const int tid  = threadIdx.x;
    const int lane = tid & 63;
    const int w    = tid >> 6;
    const int bm = blockIdx.y, bn = blockIdx.x;
    const int wm = (w >> 1) * 64;
    const int wn = (w & 1) * 64;

    f32x4 acc[4][4] = {};

    // staging: thread owns LDS chunk (row=(c&1)*64 + tid>>2, pos=tid&3);
    // fetches source chunk (tid&3) ^ ((row>>1)&3) = (tid&3) ^ ((tid>>3)&3)
    const int sfetch = (tid & 3) ^ ((tid >> 3) & 3);
    const size_t offA = (size_t)(bm * 128 + (tid >> 2)) * Kd + sfetch * 8;
    const size_t offB = (size_t)(bn * 128 + (tid >> 2)) * Kd + sfetch * 8;
    const __hip_bfloat16* pAh = Ahi + offA;
    const __hip_bfloat16* pAl = Alo + offA;
    const __hip_bfloat16* pBh = Bhi + offB;
    const __hip_bfloat16* pBl = Blo + offB;
    const size_t half = (size_t)64 * Kd;   // +64 rows
    char* dst0 = sm + tid * 16;

    // read side: fragment chunk = lane>>4, swizzled: ^ ((lane>>1)&3)
    const int rA = lane & 15;
    const int ca = (lane >> 4) ^ ((lane >> 1) & 3);
    const char* aP = sm +         (wm + rA) * 64 + ca * 16;   // A-hi base
    const char* bP = sm + 16384 + (wn + rA) * 64 + ca * 16;   // B-hi base

#define STAGE(BO, kk) do { \
    __builtin_amdgcn_global_load_lds((gas_ptr)(pAh + (kk)),        (lds_ptr_t)(dst0 + (BO)),          16, 0, 0); \
    __builtin_amdgcn_global_load_lds((gas_ptr)(pAh + half + (kk)), (lds_ptr_t)(dst0 + (BO) + 4096),   16, 0, 0); \
    __builtin_amdgcn_global_load_lds((gas_ptr)(pAl + (kk)),        (lds_ptr_t)(dst0 + (BO) + 8192),   16, 0, 0); \
    __builtin_amdgcn_global_load_lds((gas_ptr)(pAl + half + (kk)), (lds_ptr_t)(dst0 + (BO) + 12288),  16, 0, 0); \
    __builtin_amdgcn_global_load_lds((gas_ptr)(pBh + (kk)),        (lds_ptr_t)(dst0 + (BO) + 16384),  16, 0, 0); \
    __builtin_amdgcn_global_load_lds((gas_ptr)(pBh + half + (kk)), (lds_ptr_t)(dst0 + (BO) + 20480),  16, 0, 0); \
    __builtin_amdgcn_global_load_lds((gas_ptr)(pBl + (kk)),        (lds_ptr_t)(dst0 + (BO) + 24576),  16, 0, 0); \
    __builtin_amdgcn_global_load_lds((gas_ptr)(pBl + half + (kk)), (lds_ptr_t)(dst0 + (BO) + 28672),  16, 0, 0); \
} while (0)

#define COMPUTE(BO) do { \
    bf16x8 bh[4], bl[4]; \
    _Pragma("unroll") \
    for (int j = 0; j < 4; ++j) { \
        bh[j] = *(const bf16x8*)(bP + (BO) + j * 1024); \
        bl[j] = *(const bf16x8*)(bP + (BO) + j * 1024 + 8192); \
    } \
    __builtin_amdgcn_s_setprio(1); \
    _Pragma("unroll") \
    for (int i = 0; i < 4; ++i) { \
        bf16x8 ah = *(const bf16x8*)(aP + (BO) + i * 1024); \
        bf16x8 al = *(const bf16x8*)(aP + (BO) + i * 1024 + 8192); \
        _Pragma("unroll") \
        for (int j = 0; j < 4; ++j) { \
            acc[i][j] = __builtin_amdgcn_mfma_f32_16x16x32_bf16(ah, bh[j], acc[i][j], 0, 0, 0); \
            acc[i][j] = __builtin_amdgcn_mfma_f32_16x16x32_bf16(al, bh[j], acc[i][j], 0, 0, 0); \
            acc[i][j] = __builtin_amdgcn_mfma_f32_16x16x32_bf16(ah, bl[j], acc[i][j], 0, 0, 0); \
        } \
    } \
    __builtin_amdgcn_s_setprio(0); \
} while (0)

    // Pipeline: stage t+1 into the other buffer, wait own vmcnt to 8
    // (current buffer's 8 loads landed), barrier, compute; barrier before
    // the buffer can be overwritten. vmcnt never drains to 0 in the loop.
    STAGE(0, 0);
#pragma unroll 2
    for (int k0 = 0; k0 < Kd - 64; k0 += 64) {
        STAGE(32768, k0 + 32);
        wait_vm8_bar();
        COMPUTE(0);
        bar_only();
        STAGE(0, k0 + 64);
        wait_vm8_bar();
        COMPUTE(32768);
        bar_only();
    }
    // tail: k0 = Kd-64
    STAGE(32768, Kd - 32);
    wait_vm8_bar();
    COMPUTE(0);
    bar_only();
    wait_vm0_bar();
    COMPUTE(32768);

#undef STAGE
#undef COMPUTE

    // Epilogue: 16x16 C/D layout col=lane&15, row=(lane>>4)*4+reg (m89/m91).
    // NT stores: C is 256 MB (> L3), zero reuse before softmax streams it.
    const int r0 = bm * 128 + wm + ((lane >> 4) << 2);
    const int c0 = bn * 128 + wn + rA;
#pragma unroll
    for (int i = 0; i < 4; ++i)
#pragma unroll
        for (int j = 0; j < 4; ++j)
#pragma unroll
            for (int r = 0; r < 4; ++r)
                __builtin_nontemporal_store(
                    acc[i][j][r],
                    &out[(size_t)(r0 + i * 16 + r) * Nd + (c0 + j * 16)]);
}

// ---------------------------------------------------------------------------
// Kernel 2b (fallback, ws too small — not expected to run): inline split.
// ---------------------------------------------------------------------------
__global__ __launch_bounds__(256) void gemm_fallback(
    const float* __restrict__ Af, const float* __restrict__ Bf,
    float* __restrict__ out, int M, int N, int K)
{
    __shared__ char sm[32768];
    const int tid  = threadIdx.x;
    const int lane = tid & 63;
    const int w    = tid >> 6;
    const int bm = blockIdx.y, bn = blockIdx.x;
    const int wm = (w >> 1) * 64;
    const int wn = (w & 1) * 64;

    f32x4 acc[4][4] = {};
    const int sfetch = (tid & 3) ^ ((tid >> 3) & 3);
    const int rA = lane & 15;
    const int ca = (lane >> 4) ^ ((lane >> 1) & 3);
    const char* aP = sm +         (wm + rA) * 64 + ca * 16;
    const char* bP = sm + 16384 + (wn + rA) * 64 + ca * 16;

    for (int k0 = 0; k0 < K; k0 += 32) {
        __syncthreads();
#pragma unroll
        for (int c = 0; c < 4; ++c) {
            const bool isA = (c < 2);
            const int row = ((c & 1) << 6) + (tid >> 2);
            const float* src = (isA ? Af + (size_t)(bm * 128 + row) * K
                                    : Bf + (size_t)(bn * 128 + row) * K)
                               + k0 + ((tid & 3) << 3);
            f32x4 v0 = *(const f32x4*)src;
            f32x4 v1 = *(const f32x4*)(src + 4);
            float vv[8] = {v0.x, v0.y, v0.z, v0.w, v1.x, v1.y, v1.z, v1.w};
            bf16x8 h, l;
#pragma unroll
            for (int j = 0; j < 8; ++j) {
                unsigned short hb = f32_to_bf16_rtn(vv[j]);
                unsigned short lb = f32_to_bf16_rtn(vv[j] - bf16_bits_to_f32(hb));
                h[j] = (short)hb; l[j] = (short)lb;
            }
            const int g = row * 64 + sfetch * 16;
            *(bf16x8*)(sm + (isA ? 0 : 16384) + g) = h;
            *(bf16x8*)(sm + (isA ? 8192 : 24576) + g) = l;
        }
        __syncthreads();

        bf16x8 bh[4], bl[4];
#pragma unroll
        for (int j = 0; j < 4; ++j) {
            bh[j] = *(const bf16x8*)(bP + j * 1024);
            bl[j] = *(const bf16x8*)(bP + j * 1024 + 8192);
        }
#pragma unroll
        for (int i = 0; i < 4; ++i) {
            bf16x8 ah = *(const bf16x8*)(aP + i * 1024);
            bf16x8 al = *(const bf16x8*)(aP + i * 1024 + 8192);
#pragma unroll
            for (int j = 0; j < 4; ++j) {
                acc[i][j] = __builtin_amdgcn_mfma_f32_16x16x32_bf16(ah, bh[j], acc[i][j], 0, 0, 0);
                acc[i][j] = __builtin_amdgcn_mfma_f32_16x16x32_bf16(al, bh[j], acc[i][j], 0, 0, 0);
                acc[i][j] = __builtin_amdgcn_mfma_f32_16x16x32_bf16(ah, bl[j], acc[i][j], 0, 0, 0);
            }
        }
    }

    const int r0 = bm * 128 + wm + ((lane >> 4) << 2);
    const int c0 = bn * 128 + wn + rA;
#pragma unroll
    for (int i = 0; i < 4; ++i)
#pragma unroll
        for (int j = 0; j < 4; ++j)
#pragma unroll
            for (int r = 0; r < 4; ++r)
                __builtin_nontemporal_store(
                    acc[i][j][r],
                    &out[(size_t)(r0 + i * 16 + r) * N + (c0 + j * 16)]);
}

// ---------------------------------------------------------------------------
// Kernel 3: in-place row softmax. r0/r1/r3 structural variants all measured
// the same non-gemm remainder (~320-370 us) -> dominated by fixed harness
// overhead (+ ~90us of real BW). Frozen at the r3 version.
// ---------------------------------------------------------------------------
__device__ __forceinline__ void lgkm_barrier()
{
    asm volatile("s_waitcnt lgkmcnt(0)" ::: "memory");
    __builtin_amdgcn_s_barrier();
    asm volatile("" ::: "memory");
}

__device__ __forceinline__ void softmax_row(
    f32x4 (&v)[8], f32x4 (&vn)[8], const f32x4* __restrict__ pn, bool pref,
    f32x4* __restrict__ pout, int tid, int slot,
    float (*smax)[4], float (*ssum)[4])
{
    if (pref) {
#pragma unroll
        for (int i = 0; i < 8; ++i) vn[i] = pn[tid + (i << 8)];
    }
    float m = -3.402823466e+38f;
#pragma unroll
    for (int i = 0; i < 8; ++i)
        m = fmaxf(m, fmaxf(fmaxf(v[i].x, v[i].y), fmaxf(v[i].z, v[i].w)));
#pragma unroll
    for (int o = 32; o >= 1; o >>= 1) m = fmaxf(m, __shfl_xor(m, o));
    if ((tid & 63) == 0) smax[slot][tid >> 6] = m;
    lgkm_barrier();
    m = fmaxf(fmaxf(smax[slot][0], smax[slot][1]), fmaxf(smax[slot][2], smax[slot][3]));

    float s = 0.f;
#pragma unroll
    for (int i = 0; i < 8; ++i) {
        v[i].x = __expf(v[i].x - m);
        v[i].y = __expf(v[i].y - m);
        v[i].z = __expf(v[i].z - m);
        v[i].w = __expf(v[i].w - m);
        s += (v[i].x + v[i].y) + (v[i].z + v[i].w);
    }
#pragma unroll
    for (int o = 32; o >= 1; o >>= 1) s += __shfl_xor(s, o);
    if ((tid & 63) == 0) ssum[slot][tid >> 6] = s;
    lgkm_barrier();
    s = (ssum[slot][0] + ssum[slot][1]) + (ssum[slot][2] + ssum[slot][3]);
    const float r = 1.0f / s;
#pragma unroll
    for (int i = 0; i < 8; ++i) {
        v[i] *= r;
        __builtin_nontemporal_store(v[i], &pout[tid + (i << 8)]);
    }
}

__global__ __launch_bounds__(256) void softmax_rows_8192(float* __restrict__ d)
{
    const int tid = threadIdx.x;
    __shared__ float smax[2][4], ssum[2][4];

    f32x4* p0 = (f32x4*)(d + (size_t)blockIdx.x * 4 * 8192);
    f32x4 va[8], vb[8];
#pragma unroll
    for (int i = 0; i < 8; ++i) va[i] = p0[tid + (i << 8)];

    softmax_row(va, vb, p0 + 2048, true,  p0,        tid, 0, smax, ssum);
    softmax_row(vb, va, p0 + 4096, true,  p0 + 2048, tid, 1, smax, ssum);
    softmax_row(va, vb, p0 + 6144, true,  p0 + 4096, tid, 0, smax, ssum);
    softmax_row(vb, va, p0,        false, p0 + 6144, tid, 1, smax, ssum);
}

// ---------------------------------------------------------------------------
extern "C" void kernel_launch(void* const* d_in, const int* in_sizes, int n_in,
                              void* d_out, int out_size, void* d_ws, size_t ws_size,
                              hipStream_t stream)
{
    const float* A = (const float*)d_in[0];   // user_emb [M, K] fp32
    const float* B = (const float*)d_in[1];   // id_emb   [N, K] fp32
    float* out = (float*)d_out;               // [M, N] fp32
    const int K = 1024;
    const int M = in_sizes[0] / K;
    const int N = in_sizes[1] / K;
    const size_t elemsA = (size_t)M * K;
    const size_t elemsB = (size_t)N * K;
    const size_t need = 2 * (elemsA + elemsB) * sizeof(unsigned short);

    dim3 grid(N / 128, M / 128);
    const bool presplit = (ws_size >= need) && (M == N) && (K % 64 == 0) && (K >= 128);

    if (presplit) {
        unsigned short* Ahi = (unsigned short*)d_ws;
        unsigned short* Alo = Ahi + elemsA;
        unsigned short* Bhi = Alo + elemsA;
        unsigned short* Blo = Bhi + elemsB;
        const int n4 = (int)(elemsA / 4);
        split_hi_lo<<<(n4 + 255) / 256, 256, 0, stream>>>(A, B, Ahi, Alo, Bhi, Blo, n4);
        if (K == 1024 && N == 8192) {
            gemm_presplit<1024, 8192><<<grid, 256, 0, stream>>>(
                (const __hip_bfloat16*)Ahi, (const __hip_bfloat16*)Alo,
                (const __hip_bfloat16*)Bhi, (const __hip_bfloat16*)Blo,
                out, M, N, K);
        } else {
            gemm_presplit<0, 0><<<grid, 256, 0, stream>>>(
                (const __hip_bfloat16*)Ahi, (const __hip_bfloat16*)Alo,
                (const __hip_bfloat16*)Bhi, (const __hip_bfloat16*)Blo,
                out, M, N, K);
        }
    } else {
        gemm_fallback<<<grid, 256, 0, stream>>>(A, B, out, M, N, K);
    }
    softmax_rows_8192<<<M / 4, 256, 0, stream>>>(out);
}